// Round 1
// baseline (138.910 us; speedup 1.0000x reference)
//
#include <hip/hip_runtime.h>
#include <hip/hip_bf16.h>

// KGATPGExp: out[e] = sigmoid( logit(noise[e]) + MLP(concat(emb[col],emb[row],emb[src],emb[dst])) )
// Decomposition (validated R2+, absmax 3.9e-3 vs thr 2e-2):
//   c[64]   = b1 + emb[src]@W1[256:384] + emb[dst]@W1[384:512]          (edge-invariant)
//   F[n][:] = emb[n]@W1[0:128] + c       (bf16, per node)   } fg_kernel (MFMA, HBM-bound)
//   G[n][:] = emb[n]@W1[128:256]         (bf16, per node)   }
//   out[e]  = sigmoid(logit(noise) + b2 + W2 . relu(F[col[e]] + G[row[e]]))   (edge_kernel)
// R4: cooperative fusion + per-thread fences = L2 wbinv storm (290us @ 4% HBM). Reverted.
// R5: one-thread-per-edge gathers = 64 lines/instr (8x transaction rate, 62us). Reverted.
// R6: fg launch_bounds(256,4) snuck in: 128-VGPR cap -> spills (+3us, fixed R7).
// R7: 4-octet/wave edge (BATCHED: 4 chains, one drain) ~9us slower than 1-octet.
// R8: exact R3 edge restore — 1 octet/wave, 12500 blocks, minimal per-wave work.
// R9 (this): (a) edge -> persistent waves w/ ROLLING 2-deep pipeline: idx prefetch
//     2 octets ahead, gathers 1 ahead, compute oldest. Issue order keeps waitcnts
//     counted (gather waits only its idx, compute waits only its gathers). Per-wave
//     outstanding loads 2 -> ~5 at unchanged occupancy (2048 blocks, 8/CU).
//     (b) fg epilogue: shfl_xor pair-pack + lane-parity row split -> 32 u32 stores
//     (256B/instr) instead of 64 u16 stores (128B/instr). Bit-identical values.

typedef __bf16 bf16x8 __attribute__((ext_vector_type(8)));
typedef float  f32x16 __attribute__((ext_vector_type(16)));
typedef unsigned short u16;

#define WSTR 264   // sW row stride (u16): 256 + 8 pad
#define Z16 {0.f,0.f,0.f,0.f,0.f,0.f,0.f,0.f,0.f,0.f,0.f,0.f,0.f,0.f,0.f,0.f}

__device__ __forceinline__ unsigned bfbits(float f){       // fp32 -> bf16 bits, RNE
  unsigned u = __builtin_bit_cast(unsigned, f);
  return (u + 0x7fffu + ((u >> 16) & 1u)) >> 16;
}
__device__ __forceinline__ unsigned pk2(float a, float b){ // pack 2 fp32 -> bf16x2 bits
  return bfbits(a) | (bfbits(b) << 16);
}
__device__ __forceinline__ float bflo(unsigned u){ return __builtin_bit_cast(float, u << 16); }
__device__ __forceinline__ float bfhi(unsigned u){ return __builtin_bit_cast(float, u & 0xffff0000u); }

// ---------------------------------------------------------------------------
// fg: F = emb@W1a + c, G = emb@W1b over all nodes. One 32-node tile per wave,
// 4 waves (128 nodes) per block. Per-block prologue builds the bf16 transposed
// W1[0:256] in LDS and the c vector (both from L2-hot W1).
//   A (emb rows, streamed):  lane holds A[m=lane&31][k=(lane>>5)*8+j]
//   B (sW from LDS):         lane holds B[k=(lane>>5)*8+j][n=lane&31]
//   C/D:                     col(n)=lane&31, row(m)=(r&3)+8*(r>>2)+4*(lane>>5)
// launch_bounds(256,3): 170-VGPR budget — (256,4) caps at 128 and spills (R6 lesson).
__global__ __launch_bounds__(256, 3) void fg_kernel(
    const float* __restrict__ embed, const float* __restrict__ W1,
    const float* __restrict__ b1, const int* __restrict__ srcp,
    const int* __restrict__ dstp, u16* __restrict__ F, u16* __restrict__ G, int NN)
{
  __shared__ __align__(16) u16 sW[64 * WSTR];
  __shared__ float sC[64];
  __shared__ float sRed[256];
  int tid = threadIdx.x;

  // --- prologue A: transpose W1[0:256][0:64] fp32 -> sW[n][k] bf16 (L2-hot) ---
  #pragma unroll
  for (int i = 0; i < 16; ++i){
    int idx = i * 256 + tid;               // 4096 float4 reads, fully coalesced
    int k = idx >> 4, q = idx & 15;
    float4 v = *(const float4*)(W1 + k * 64 + q * 4);
    sW[(4*q+0) * WSTR + k] = (u16)bfbits(v.x);
    sW[(4*q+1) * WSTR + k] = (u16)bfbits(v.y);
    sW[(4*q+2) * WSTR + k] = (u16)bfbits(v.z);
    sW[(4*q+3) * WSTR + k] = (u16)bfbits(v.w);
  }
  // --- prologue B: c partials, 4-way k-split across the block ---
  {
    int h = tid & 63, part = tid >> 6;
    int si = srcp[0], di = dstp[0];
    const float* se  = embed + (size_t)si * 128 + part * 32;
    const float* de  = embed + (size_t)di * 128 + part * 32;
    const float* w1s = W1 + (256 + part * 32) * 64 + h;
    const float* w1d = W1 + (384 + part * 32) * 64 + h;
    float acc = 0.f;
    #pragma unroll 8
    for (int k = 0; k < 32; ++k){
      acc += se[k] * w1s[k * 64];
      acc += de[k] * w1d[k * 64];
    }
    sRed[tid] = acc;
  }
  __syncthreads();
  if (tid < 64) sC[tid] = b1[tid] + sRed[tid] + sRed[64+tid] + sRed[128+tid] + sRed[192+tid];
  __syncthreads();

  // --- main MFMA loop ---
  int lane = tid & 63, wave = tid >> 6;
  int nl = lane & 31, h5 = lane >> 5;
  int tile = blockIdx.x * 128 + wave * 32;
  if (tile >= NN) return;                      // NN % 32 == 0; barriers already passed
  const float* erow = embed + (size_t)(tile + nl) * 128;
  f32x16 aF0 = Z16, aF1 = Z16, aG0 = Z16, aG1 = Z16;
  const u16* sw0 = sW + nl * WSTR;             // hidden rows 0..31
  const u16* sw1 = sW + (32 + nl) * WSTR;      // hidden rows 32..63
  #pragma unroll
  for (int s = 0; s < 8; ++s){                 // K = 128, 16 per MFMA
    int ko = s * 16 + h5 * 8;
    float4 x = *(const float4*)(erow + ko);
    float4 y = *(const float4*)(erow + ko + 4);
    uint4 u; u.x = pk2(x.x,x.y); u.y = pk2(x.z,x.w); u.z = pk2(y.x,y.y); u.w = pk2(y.z,y.w);
    bf16x8 a = __builtin_bit_cast(bf16x8, u);
    bf16x8 bF0 = *(const bf16x8*)(sw0 + ko);
    bf16x8 bF1 = *(const bf16x8*)(sw1 + ko);
    bf16x8 bG0 = *(const bf16x8*)(sw0 + 128 + ko);   // W1b at k=128..255
    bf16x8 bG1 = *(const bf16x8*)(sw1 + 128 + ko);
    aF0 = __builtin_amdgcn_mfma_f32_32x32x16_bf16(a, bF0, aF0, 0, 0, 0);
    aF1 = __builtin_amdgcn_mfma_f32_32x32x16_bf16(a, bF1, aF1, 0, 0, 0);
    aG0 = __builtin_amdgcn_mfma_f32_32x32x16_bf16(a, bG0, aG0, 0, 0, 0);
    aG1 = __builtin_amdgcn_mfma_f32_32x32x16_bf16(a, bG1, aG1, 0, 0, 0);
  }
  // --- epilogue (R9): pair-pack cols via shfl_xor(1); lane parity stores row r
  // (even lanes) vs row r+1 (odd lanes). 4 u32 stores per r-pair, 256B/instr.
  float cv0 = sC[nl], cv1 = sC[32 + nl];
  int lo = lane & 1;
  int nlp = nl & ~1;                           // paired col base (u16 units)
  #pragma unroll
  for (int r = 0; r < 16; r += 2){
    int ra = r + lo;                           // row this lane stores
    int node = tile + (ra & 3) + 8 * (ra >> 2) + 4 * h5;
    u16* fr = F + (size_t)node * 64 + nlp;
    u16* gr = G + (size_t)node * 64 + nlp;
    // F0 (+c), cols [nlp, nlp+1]
    float f0a = aF0[r]   + cv0;
    float f0b = aF0[r+1] + cv0;
    float f0an = __shfl_xor(f0a, 1), f0bn = __shfl_xor(f0b, 1);
    *(unsigned*)(fr)      = lo ? pk2(f0bn, f0b) : pk2(f0a, f0an);
    // F1 (+c), cols [32+nlp, 32+nlp+1]
    float f1a = aF1[r]   + cv1;
    float f1b = aF1[r+1] + cv1;
    float f1an = __shfl_xor(f1a, 1), f1bn = __shfl_xor(f1b, 1);
    *(unsigned*)(fr + 32) = lo ? pk2(f1bn, f1b) : pk2(f1a, f1an);
    // G0
    float g0a = aG0[r], g0b = aG0[r+1];
    float g0an = __shfl_xor(g0a, 1), g0bn = __shfl_xor(g0b, 1);
    *(unsigned*)(gr)      = lo ? pk2(g0bn, g0b) : pk2(g0a, g0an);
    // G1
    float g1a = aG1[r], g1b = aG1[r+1];
    float g1an = __shfl_xor(g1a, 1), g1bn = __shfl_xor(g1b, 1);
    *(unsigned*)(gr + 32) = lo ? pk2(g1bn, g1b) : pk2(g1a, g1an);
  }
}

// ---------------------------------------------------------------------------
// edge (R9): persistent waves, rolling 2-deep software pipeline.
// 8 lanes per edge (R3's winning gather shape: 8 merged line-requests/instr).
// Steady state per octet o:  issue idx(o+2)  ->  issue gathers(o+1, waits only
// idx(o+1))  ->  compute(o, waits only gathers(o)).  Gather latency is covered
// by one compute phase + one idx-load phase instead of being serial.
__global__ __launch_bounds__(256, 8) void edge_kernel(
    const u16* __restrict__ Ft, const u16* __restrict__ Gt,
    const float* __restrict__ W2, const float* __restrict__ b2,
    const float* __restrict__ noise, const int* __restrict__ col,
    const int* __restrict__ row, float* __restrict__ out, int E)
{
  int tid = threadIdx.x;
  int lane = tid & 63, wave = tid >> 6;
  int j = lane & 7, grp = lane >> 3;
  int gw = blockIdx.x * 4 + wave;              // global wave id
  int NW = gridDim.x * 4;
  int nOct = (E + 7) >> 3;
  int per  = (nOct + NW - 1) / NW;
  int o0 = gw * per;
  if (o0 >= nOct) return;                      // wave-uniform
  int o1 = o0 + per; if (o1 > nOct) o1 = nOct;

  // hoisted edge-invariant loads
  float4 w2a = ((const float4*)W2)[2 * j];
  float4 w2b = ((const float4*)W2)[2 * j + 1];
  float bb = b2[0];

#define LOADIDX(oo, ci, ri, ns) { int e_ = (oo) * 8 + grp; if (e_ >= E) e_ = E - 1; \
    ci = col[e_]; ri = row[e_]; ns = noise[e_]; }
#define GATHER(ci, ri, fv, gv) { \
    fv = ((const uint4*)(Ft + (size_t)(ci) * 64))[j]; \
    gv = ((const uint4*)(Gt + (size_t)(ri) * 64))[j]; }
#define COMPUTE(oo, fv, gv, ns) { \
    float p = 0.f, h; \
    h = fmaxf(bflo(fv.x) + bflo(gv.x), 0.f); p += h * w2a.x; \
    h = fmaxf(bfhi(fv.x) + bfhi(gv.x), 0.f); p += h * w2a.y; \
    h = fmaxf(bflo(fv.y) + bflo(gv.y), 0.f); p += h * w2a.z; \
    h = fmaxf(bfhi(fv.y) + bfhi(gv.y), 0.f); p += h * w2a.w; \
    h = fmaxf(bflo(fv.z) + bflo(gv.z), 0.f); p += h * w2b.x; \
    h = fmaxf(bfhi(fv.z) + bfhi(gv.z), 0.f); p += h * w2b.y; \
    h = fmaxf(bflo(fv.w) + bflo(gv.w), 0.f); p += h * w2b.z; \
    h = fmaxf(bfhi(fv.w) + bfhi(gv.w), 0.f); p += h * w2b.w; \
    p += __shfl_xor(p, 1, 64); \
    p += __shfl_xor(p, 2, 64); \
    p += __shfl_xor(p, 4, 64); \
    int e_ = (oo) * 8 + grp; \
    if (j == 0 && e_ < E){ \
      float g_ = logf(ns) - log1pf(-ns) + p + bb; \
      out[e_] = 1.f / (1.f + expf(-g_)); \
    } }

  int o = o0;
  // pipeline prologue: idx(o), idx(o+1), gathers(o)
  int ciA, riA; float nsA; LOADIDX(o,     ciA, riA, nsA);
  int ciB, riB; float nsB; LOADIDX(o + 1, ciB, riB, nsB);   // clamped-safe if o+1>=nOct
  uint4 fC, gC; GATHER(ciA, riA, fC, gC);
  float nsC = nsA;

  #pragma unroll 2
  for (; o + 1 < o1; ++o){
    int ciN, riN; float nsN; LOADIDX(o + 2, ciN, riN, nsN); // prefetch idx 2 ahead
    uint4 fN, gN; GATHER(ciB, riB, fN, gN);                 // gathers 1 ahead
    COMPUTE(o, fC, gC, nsC);                                // compute oldest
    fC = fN; gC = gN; nsC = nsB;                            // rotate slots
    ciB = ciN; riB = riN; nsB = nsN;
  }
  COMPUTE(o, fC, gC, nsC);

#undef LOADIDX
#undef GATHER
#undef COMPUTE
}

// ---------------------------------------------------------------------------
// Insurance path if ws_size is too small for F/G tables: correct-but-slow fp32.
__global__ void naive_kernel(const float* __restrict__ embed, const float* __restrict__ W1,
    const float* __restrict__ b1, const float* __restrict__ W2, const float* __restrict__ b2,
    const float* __restrict__ noise, const int* __restrict__ col, const int* __restrict__ row,
    const int* __restrict__ srcp, const int* __restrict__ dstp, float* __restrict__ out, int E)
{
  int e = blockIdx.x * 256 + threadIdx.x;
  if (e >= E) return;
  int ci = col[e], ri = row[e], si = srcp[0], di = dstp[0];
  const float* ce = embed + (size_t)ci * 128;
  const float* re = embed + (size_t)ri * 128;
  const float* se = embed + (size_t)si * 128;
  const float* de = embed + (size_t)di * 128;
  float w = b2[0];
  for (int jj = 0; jj < 64; ++jj){
    float hh = b1[jj];
    for (int k = 0; k < 128; ++k){
      hh += ce[k] * W1[k * 64 + jj] + re[k] * W1[(128 + k) * 64 + jj]
          + se[k] * W1[(256 + k) * 64 + jj] + de[k] * W1[(384 + k) * 64 + jj];
    }
    w += fmaxf(hh, 0.f) * W2[jj];
  }
  float ns = noise[e];
  float g = logf(ns) - log1pf(-ns) + w;
  out[e] = 1.f / (1.f + expf(-g));
}

// ---------------------------------------------------------------------------
extern "C" void kernel_launch(void* const* d_in, const int* in_sizes, int n_in,
                              void* d_out, int out_size, void* d_ws, size_t ws_size,
                              hipStream_t stream)
{
  const float* embed = (const float*)d_in[0];
  const float* W1    = (const float*)d_in[1];
  const float* b1    = (const float*)d_in[2];
  const float* W2    = (const float*)d_in[3];
  const float* b2    = (const float*)d_in[4];
  const float* noise = (const float*)d_in[5];
  const int*   col   = (const int*)d_in[6];
  const int*   rowp  = (const int*)d_in[7];
  const int*   srcp  = (const int*)d_in[8];
  const int*   dstp  = (const int*)d_in[9];
  const int E  = in_sizes[5];
  const int NN = in_sizes[0] / 128;
  float* out = (float*)d_out;

  const size_t fBytes = (size_t)NN * 64 * sizeof(u16);
  if (ws_size >= 2 * fBytes){
    u16* F = (u16*)d_ws;
    u16* G = (u16*)((char*)d_ws + fBytes);
    fg_kernel<<<(NN + 127) / 128, 256, 0, stream>>>(embed, W1, b1, srcp, dstp, F, G, NN);
    edge_kernel<<<2048, 256, 0, stream>>>(F, G, W2, b2, noise, col, rowp, out, E);
  } else {
    naive_kernel<<<(E + 255) / 256, 256, 0, stream>>>(embed, W1, b1, W2, b2, noise,
                                                      col, rowp, srcp, dstp, out, E);
  }
}

// Round 3
// 135.258 us; speedup vs baseline: 1.0270x; 1.0270x over previous
//
#include <hip/hip_runtime.h>
#include <hip/hip_bf16.h>

// KGATPGExp: out[e] = sigmoid( logit(noise[e]) + MLP(concat(emb[col],emb[row],emb[src],emb[dst])) )
// Decomposition (validated R2+):
//   c[64]   = b1 + emb[src]@W1[256:384] + emb[dst]@W1[384:512]          (edge-invariant)
//   F[n][:] = emb[n]@W1[0:128] + c       (fp8, per node)   } fg_kernel (MFMA, HBM-bound)
//   G[n][:] = emb[n]@W1[128:256]         (fp8, per node)   }
//   out[e]  = sigmoid(logit(noise) + b2 + W2 . relu(F[col[e]] + G[row[e]]))   (edge_kernel)
// R4: cooperative fusion + per-thread fences = L2 wbinv storm (290us @ 4% HBM). Reverted.
// R5: one-thread-per-edge gathers = 64 lines/instr (32x request rate, only 1.8x time
//     -> edge is BYTES-bound at LLC, not transaction-bound).
// R6: fg launch_bounds(256,4): 128-VGPR cap -> spills. Keep (256,3).
// R7: 4-octet/wave batched edge: +9us (drain-point batching). Reverted.
// R8: R3 edge restore — 1 octet/wave, 12500 blocks. Best verified shape.
// R9: rolling 2-deep pipeline + persistent 2048 blocks: NEUTRAL (+2us). Edge is not
//     wave-latency-bound. Reverted to R8 grid. fg pair-packed epilogue kept.
// R10: F/G tables fp8 e4m3. COMPILE FAIL: cvt_pk_f32_fp8 word-select must be a
//      constant int — runtime bool through a helper doesn't fold.
// R11 (this): same as R10 with template<bool HI> decode helper (constant at each
//      instantiation). Gather stream 102->51 MB, tables 25.6->12.8 MB.

typedef __bf16 bf16x8 __attribute__((ext_vector_type(8)));
typedef float  f32x16 __attribute__((ext_vector_type(16)));
typedef float  f32x2  __attribute__((ext_vector_type(2)));
typedef unsigned short u16;
typedef unsigned char  u8;

#define WSTR 264   // sW row stride (u16): 256 + 8 pad
#define Z16 {0.f,0.f,0.f,0.f,0.f,0.f,0.f,0.f,0.f,0.f,0.f,0.f,0.f,0.f,0.f,0.f}

__device__ __forceinline__ unsigned bfbits(float f){       // fp32 -> bf16 bits, RNE
  unsigned u = __builtin_bit_cast(unsigned, f);
  return (u + 0x7fffu + ((u >> 16) & 1u)) >> 16;
}
__device__ __forceinline__ unsigned pk2(float a, float b){ // pack 2 fp32 -> bf16x2 bits
  return bfbits(a) | (bfbits(b) << 16);
}
// fp8 e4m3 HW converts (gfx950 OCP format; encode/decode self-consistent)
__device__ __forceinline__ u16 pkf8(float a, float b){
  return (u16)__builtin_amdgcn_cvt_pk_fp8_f32(a, b, 0, false);  // byte0=a, byte1=b
}
template<bool HI>
__device__ __forceinline__ f32x2 upf8(unsigned w){
  return __builtin_amdgcn_cvt_pk_f32_fp8((int)w, HI);           // bytes (0,1) or (2,3)
}

// ---------------------------------------------------------------------------
// fg: F = emb@W1a + c, G = emb@W1b over all nodes. One 32-node tile per wave,
// 4 waves (128 nodes) per block. Per-block prologue builds the bf16 transposed
// W1[0:256] in LDS and the c vector (both from L2-hot W1).
//   A (emb rows, streamed):  lane holds A[m=lane&31][k=(lane>>5)*8+j]
//   B (sW from LDS):         lane holds B[k=(lane>>5)*8+j][n=lane&31]
//   C/D:                     col(n)=lane&31, row(m)=(r&3)+8*(r>>2)+4*(lane>>5)
// launch_bounds(256,3): 170-VGPR budget — (256,4) caps at 128 and spills (R6 lesson).
__global__ __launch_bounds__(256, 3) void fg_kernel(
    const float* __restrict__ embed, const float* __restrict__ W1,
    const float* __restrict__ b1, const int* __restrict__ srcp,
    const int* __restrict__ dstp, u8* __restrict__ F, u8* __restrict__ G, int NN)
{
  __shared__ __align__(16) u16 sW[64 * WSTR];
  __shared__ float sC[64];
  __shared__ float sRed[256];
  int tid = threadIdx.x;

  // --- prologue A: transpose W1[0:256][0:64] fp32 -> sW[n][k] bf16 (L2-hot) ---
  #pragma unroll
  for (int i = 0; i < 16; ++i){
    int idx = i * 256 + tid;               // 4096 float4 reads, fully coalesced
    int k = idx >> 4, q = idx & 15;
    float4 v = *(const float4*)(W1 + k * 64 + q * 4);
    sW[(4*q+0) * WSTR + k] = (u16)bfbits(v.x);
    sW[(4*q+1) * WSTR + k] = (u16)bfbits(v.y);
    sW[(4*q+2) * WSTR + k] = (u16)bfbits(v.z);
    sW[(4*q+3) * WSTR + k] = (u16)bfbits(v.w);
  }
  // --- prologue B: c partials, 4-way k-split across the block ---
  {
    int h = tid & 63, part = tid >> 6;
    int si = srcp[0], di = dstp[0];
    const float* se  = embed + (size_t)si * 128 + part * 32;
    const float* de  = embed + (size_t)di * 128 + part * 32;
    const float* w1s = W1 + (256 + part * 32) * 64 + h;
    const float* w1d = W1 + (384 + part * 32) * 64 + h;
    float acc = 0.f;
    #pragma unroll 8
    for (int k = 0; k < 32; ++k){
      acc += se[k] * w1s[k * 64];
      acc += de[k] * w1d[k * 64];
    }
    sRed[tid] = acc;
  }
  __syncthreads();
  if (tid < 64) sC[tid] = b1[tid] + sRed[tid] + sRed[64+tid] + sRed[128+tid] + sRed[192+tid];
  __syncthreads();

  // --- main MFMA loop ---
  int lane = tid & 63, wave = tid >> 6;
  int nl = lane & 31, h5 = lane >> 5;
  int tile = blockIdx.x * 128 + wave * 32;
  if (tile >= NN) return;                      // NN % 32 == 0; barriers already passed
  const float* erow = embed + (size_t)(tile + nl) * 128;
  f32x16 aF0 = Z16, aF1 = Z16, aG0 = Z16, aG1 = Z16;
  const u16* sw0 = sW + nl * WSTR;             // hidden rows 0..31
  const u16* sw1 = sW + (32 + nl) * WSTR;      // hidden rows 32..63
  #pragma unroll
  for (int s = 0; s < 8; ++s){                 // K = 128, 16 per MFMA
    int ko = s * 16 + h5 * 8;
    float4 x = *(const float4*)(erow + ko);
    float4 y = *(const float4*)(erow + ko + 4);
    uint4 u; u.x = pk2(x.x,x.y); u.y = pk2(x.z,x.w); u.z = pk2(y.x,y.y); u.w = pk2(y.z,y.w);
    bf16x8 a = __builtin_bit_cast(bf16x8, u);
    bf16x8 bF0 = *(const bf16x8*)(sw0 + ko);
    bf16x8 bF1 = *(const bf16x8*)(sw1 + ko);
    bf16x8 bG0 = *(const bf16x8*)(sw0 + 128 + ko);   // W1b at k=128..255
    bf16x8 bG1 = *(const bf16x8*)(sw1 + 128 + ko);
    aF0 = __builtin_amdgcn_mfma_f32_32x32x16_bf16(a, bF0, aF0, 0, 0, 0);
    aF1 = __builtin_amdgcn_mfma_f32_32x32x16_bf16(a, bF1, aF1, 0, 0, 0);
    aG0 = __builtin_amdgcn_mfma_f32_32x32x16_bf16(a, bG0, aG0, 0, 0, 0);
    aG1 = __builtin_amdgcn_mfma_f32_32x32x16_bf16(a, bG1, aG1, 0, 0, 0);
  }
  // --- epilogue: shfl_xor pair-pack cols; lane parity picks row r / r+1.
  // fp8 pack: u16 = 2 adjacent cols. 32 u16 stores per lane total.
  float cv0 = sC[nl], cv1 = sC[32 + nl];
  int lo = lane & 1;
  int nlp = nl & ~1;                           // paired col base
  #pragma unroll
  for (int r = 0; r < 16; r += 2){
    int ra = r + lo;                           // row this lane stores
    int node = tile + (ra & 3) + 8 * (ra >> 2) + 4 * h5;
    u8* fr = F + (size_t)node * 64 + nlp;
    u8* gr = G + (size_t)node * 64 + nlp;
    float f0a = aF0[r]   + cv0;
    float f0b = aF0[r+1] + cv0;
    float f0an = __shfl_xor(f0a, 1), f0bn = __shfl_xor(f0b, 1);
    *(u16*)(fr)      = lo ? pkf8(f0bn, f0b) : pkf8(f0a, f0an);
    float f1a = aF1[r]   + cv1;
    float f1b = aF1[r+1] + cv1;
    float f1an = __shfl_xor(f1a, 1), f1bn = __shfl_xor(f1b, 1);
    *(u16*)(fr + 32) = lo ? pkf8(f1bn, f1b) : pkf8(f1a, f1an);
    float g0a = aG0[r], g0b = aG0[r+1];
    float g0an = __shfl_xor(g0a, 1), g0bn = __shfl_xor(g0b, 1);
    *(u16*)(gr)      = lo ? pkf8(g0bn, g0b) : pkf8(g0a, g0an);
    float g1a = aG1[r], g1b = aG1[r+1];
    float g1an = __shfl_xor(g1a, 1), g1bn = __shfl_xor(g1b, 1);
    *(u16*)(gr + 32) = lo ? pkf8(g1bn, g1b) : pkf8(g1a, g1an);
  }
}

// ---------------------------------------------------------------------------
// edge (R8 shape, fp8 rows): 8 lanes per edge, lane j reads 8 B chunk j of the
// 64 B F/G row (8 merged 64-B segments per gather instruction). ONE octet per
// wave, no loop — 50K waves of minimal work; TLP hides the gather latency.
__global__ __launch_bounds__(256, 8) void edge_kernel(
    const u8* __restrict__ Ft, const u8* __restrict__ Gt,
    const float* __restrict__ W2, const float* __restrict__ b2,
    const float* __restrict__ noise, const int* __restrict__ col,
    const int* __restrict__ row, float* __restrict__ out, int E)
{
  int tid = threadIdx.x;
  int lane = tid & 63, wave = tid >> 6;
  int j = lane & 7, grp = lane >> 3;
  int e0 = blockIdx.x * 32 + wave * 8;
  if (e0 >= E) return;                         // wave-uniform
  int e = e0 + grp; if (e >= E) e = E - 1;     // clamp (safe read), store masked below
  int ci = col[e], ri = row[e];
  uint2 fv = ((const uint2*)(Ft + (size_t)ci * 64))[j];
  uint2 gv = ((const uint2*)(Gt + (size_t)ri * 64))[j];
  float4 w2a = ((const float4*)W2)[2 * j];
  float4 w2b = ((const float4*)W2)[2 * j + 1];
  f32x2 f01 = upf8<false>(fv.x), f23 = upf8<true>(fv.x);
  f32x2 f45 = upf8<false>(fv.y), f67 = upf8<true>(fv.y);
  f32x2 g01 = upf8<false>(gv.x), g23 = upf8<true>(gv.x);
  f32x2 g45 = upf8<false>(gv.y), g67 = upf8<true>(gv.y);
  float p = 0.f, h;
  h = fmaxf(f01[0] + g01[0], 0.f); p += h * w2a.x;
  h = fmaxf(f01[1] + g01[1], 0.f); p += h * w2a.y;
  h = fmaxf(f23[0] + g23[0], 0.f); p += h * w2a.z;
  h = fmaxf(f23[1] + g23[1], 0.f); p += h * w2a.w;
  h = fmaxf(f45[0] + g45[0], 0.f); p += h * w2b.x;
  h = fmaxf(f45[1] + g45[1], 0.f); p += h * w2b.y;
  h = fmaxf(f67[0] + g67[0], 0.f); p += h * w2b.z;
  h = fmaxf(f67[1] + g67[1], 0.f); p += h * w2b.w;
  p += __shfl_xor(p, 1, 64);
  p += __shfl_xor(p, 2, 64);
  p += __shfl_xor(p, 4, 64);
  if (j == 0 && e0 + grp < E){
    float ns = noise[e];
    float g = logf(ns) - log1pf(-ns) + p + b2[0];
    out[e] = 1.f / (1.f + expf(-g));
  }
}

// ---------------------------------------------------------------------------
// Insurance path if ws_size is too small for F/G tables: correct-but-slow fp32.
__global__ void naive_kernel(const float* __restrict__ embed, const float* __restrict__ W1,
    const float* __restrict__ b1, const float* __restrict__ W2, const float* __restrict__ b2,
    const float* __restrict__ noise, const int* __restrict__ col, const int* __restrict__ row,
    const int* __restrict__ srcp, const int* __restrict__ dstp, float* __restrict__ out, int E)
{
  int e = blockIdx.x * 256 + threadIdx.x;
  if (e >= E) return;
  int ci = col[e], ri = row[e], si = srcp[0], di = dstp[0];
  const float* ce = embed + (size_t)ci * 128;
  const float* re = embed + (size_t)ri * 128;
  const float* se = embed + (size_t)si * 128;
  const float* de = embed + (size_t)di * 128;
  float w = b2[0];
  for (int jj = 0; jj < 64; ++jj){
    float hh = b1[jj];
    for (int k = 0; k < 128; ++k){
      hh += ce[k] * W1[k * 64 + jj] + re[k] * W1[(128 + k) * 64 + jj]
          + se[k] * W1[(256 + k) * 64 + jj] + de[k] * W1[(384 + k) * 64 + jj];
    }
    w += fmaxf(hh, 0.f) * W2[jj];
  }
  float ns = noise[e];
  float g = logf(ns) - log1pf(-ns) + w;
  out[e] = 1.f / (1.f + expf(-g));
}

// ---------------------------------------------------------------------------
extern "C" void kernel_launch(void* const* d_in, const int* in_sizes, int n_in,
                              void* d_out, int out_size, void* d_ws, size_t ws_size,
                              hipStream_t stream)
{
  const float* embed = (const float*)d_in[0];
  const float* W1    = (const float*)d_in[1];
  const float* b1    = (const float*)d_in[2];
  const float* W2    = (const float*)d_in[3];
  const float* b2    = (const float*)d_in[4];
  const float* noise = (const float*)d_in[5];
  const int*   col   = (const int*)d_in[6];
  const int*   rowp  = (const int*)d_in[7];
  const int*   srcp  = (const int*)d_in[8];
  const int*   dstp  = (const int*)d_in[9];
  const int E  = in_sizes[5];
  const int NN = in_sizes[0] / 128;
  float* out = (float*)d_out;

  const size_t fBytes = (size_t)NN * 64 * sizeof(u8);
  if (ws_size >= 2 * fBytes){
    u8* F = (u8*)d_ws;
    u8* G = (u8*)((char*)d_ws + fBytes);
    fg_kernel<<<(NN + 127) / 128, 256, 0, stream>>>(embed, W1, b1, srcp, dstp, F, G, NN);
    edge_kernel<<<(E + 31) / 32, 256, 0, stream>>>(F, G, W2, b2, noise, col, rowp, out, E);
  } else {
    naive_kernel<<<(E + 255) / 256, 256, 0, stream>>>(embed, W1, b1, W2, b2, noise,
                                                      col, rowp, srcp, dstp, out, E);
  }
}